// Round 1
// 232.395 us; speedup vs baseline: 1.0002x; 1.0002x over previous
//
#include <hip/hip_runtime.h>
#include <hip/hip_bf16.h>

typedef __bf16 v8bf __attribute__((ext_vector_type(8)));
typedef float v4f __attribute__((ext_vector_type(4)));

#define GBL_AS(p) ((const __attribute__((address_space(1))) unsigned int*)(p))
#define LDS_AS(p) ((__attribute__((address_space(3))) unsigned int*)(p))

// s_waitcnt immediates: lgkmcnt=15 (no wait) bits[11:8], expcnt=7 bits[6:4],
// vmcnt low bits[3:0].
#define WAIT_VM4() __builtin_amdgcn_s_waitcnt(0x0F74)  // vmcnt(4)
#define WAIT_VM6() __builtin_amdgcn_s_waitcnt(0x0F76)  // vmcnt(6)
#define WAIT_VM0() __builtin_amdgcn_s_waitcnt(0x0F70)  // vmcnt(0)

// ---------------- fp32 -> bf16 cast (x) ----------------
__global__ void cast_f32_bf16(const float* __restrict__ src,
                              __hip_bfloat16* __restrict__ dst, int n) {
  int i = (blockIdx.x * 256 + threadIdx.x) * 4;
  if (i >= n) return;
  float4 f = *(const float4*)(src + i);
  union { __hip_bfloat16 h[4]; uint2 u; } pk;
  pk.h[0] = __float2bfloat16(f.x);
  pk.h[1] = __float2bfloat16(f.y);
  pk.h[2] = __float2bfloat16(f.z);
  pk.h[3] = __float2bfloat16(f.w);
  *(uint2*)(dst + i) = pk.u;
}

// ---------------- fp32 -> bf16 cast, 3 weight tensors in one dispatch ----------------
__global__ void cast_w3(const float* __restrict__ a, const float* __restrict__ b,
                        const float* __restrict__ c, __hip_bfloat16* __restrict__ dst) {
  int seg = blockIdx.x >> 10;
  const float* src = seg == 0 ? a : (seg == 1 ? b : c);
  int i = ((blockIdx.x & 1023) * 256 + threadIdx.x) * 4;
  float4 f = *(const float4*)(src + i);
  union { __hip_bfloat16 h[4]; uint2 u; } pk;
  pk.h[0] = __float2bfloat16(f.x);
  pk.h[1] = __float2bfloat16(f.y);
  pk.h[2] = __float2bfloat16(f.z);
  pk.h[3] = __float2bfloat16(f.w);
  *(uint2*)(dst + seg * 1048576 + i) = pk.u;
}

// ---------------- NT GEMM body (scores / PV), 128x128 tile, 4 waves of 64x64 ----
// Unchanged proven structure from the 232us kernel; split into named __global__
// wrappers (gemm_score / gemm_pv) purely for rocprof attribution.
// LDS XOR-swizzle: 16B chunk (row r, col-chunk c) lives at chunk r*4 + (c ^ ((r>>1)&3)).
// MODE 1: scores->P. triangular grid (544). p=(n<=m)?exp(s*scale):0, fused
//         row-sum atomicAdd.
// MODE 2: PV (dynamic K). paired grid (512), mirrored mb. fp32 out / sums[m].
template<int MODE>
__device__ static __forceinline__
void gemm_nt_body(const __hip_bfloat16* __restrict__ A, long sAb, int lda,
                  const __hip_bfloat16* __restrict__ B, long sBb, int ldb,
                  void* __restrict__ Cv, long sCb, int ldc,
                  int K, float scale, float* __restrict__ sums) {
  const int tid = threadIdx.x;
  const int l = tid & 63, w = tid >> 6;
  int z, nb, mb, kend = K;
  if (MODE == 1) {
    const int id = blockIdx.x;
    z = id & 3;
    const int t = id >> 2;                         // 0..135 triangular index
    int m = (int)((__builtin_sqrtf(8.0f * t + 1.0f) - 1.0f) * 0.5f);
    while ((m + 1) * (m + 2) / 2 <= t) ++m;
    while (m * (m + 1) / 2 > t) --m;
    mb = m << 7;
    nb = (t - m * (m + 1) / 2) << 7;
  } else {
    const int id = blockIdx.x;
    const int half = id >> 8, r8 = id & 255;
    const int m = r8 >> 4, low = r8 & 15;
    nb = (low >> 1) << 7;
    z = (half << 1) | (low & 1);
    const int mi = half ? (15 - m) : m;            // mirrored: pair work constant
    mb = mi << 7;
    kend = (mi + 1) << 7;                          // causal K-limit
  }

  A += (long)z * sAb;
  B += (long)z * sBb;

  __shared__ alignas(16) __hip_bfloat16 As[3][128 * 32];
  __shared__ alignas(16) __hip_bfloat16 Bs[3][128 * 32];

  v4f acc[4][4] = {};
  const int wm = (w >> 1) * 64, wn = (w & 1) * 64;

  // staging: lane l fills LDS chunk q = cb + l; that chunk holds global
  // (row = q>>2, col-chunk = (q&3) ^ ((row>>1)&3))   [swizzle inverse]
  const int cb0 = w * 64;
  const int q0 = cb0 + l, r0s = q0 >> 2;
  const int c0s = ((q0 & 3) ^ ((r0s >> 1) & 3)) << 3;
  const int cb1 = 256 + w * 64;
  const int q1 = cb1 + l, r1s = q1 >> 2;
  const int c1s = ((q1 & 3) ^ ((r1s >> 1) & 3)) << 3;

  const __hip_bfloat16* Arow0 = A + (long)(mb + r0s) * lda + c0s;
  const __hip_bfloat16* Arow1 = A + (long)(mb + r1s) * lda + c1s;
  const __hip_bfloat16* Brow0 = B + (long)(nb + r0s) * ldb + c0s;
  const __hip_bfloat16* Brow1 = B + (long)(nb + r1s) * ldb + c1s;

  // swizzled LDS read bases: row = wm/wn + (l&15), col-chunk = l>>4
  const int arow = wm + (l & 15);
  const int ldsA = arow * 32 + ((((l >> 4) ^ ((arow >> 1) & 3))) << 3);
  const int brow = wn + (l & 15);
  const int ldsB = brow * 32 + ((((l >> 4) ^ ((brow >> 1) & 3))) << 3);

#define STAGE_T(K0, BUF) do {                                                   \
    __builtin_amdgcn_global_load_lds(GBL_AS(Arow0 + (K0)),                      \
        LDS_AS(&As[BUF][cb0 * 8]), 16, 0, 0);                                   \
    __builtin_amdgcn_global_load_lds(GBL_AS(Brow0 + (K0)),                      \
        LDS_AS(&Bs[BUF][cb0 * 8]), 16, 0, 0);                                   \
    __builtin_amdgcn_global_load_lds(GBL_AS(Arow1 + (K0)),                      \
        LDS_AS(&As[BUF][cb1 * 8]), 16, 0, 0);                                   \
    __builtin_amdgcn_global_load_lds(GBL_AS(Brow1 + (K0)),                      \
        LDS_AS(&Bs[BUF][cb1 * 8]), 16, 0, 0);                                   \
  } while (0)

#define COMPUTE(BI) do {                                                        \
    v8bf af[4], bfr[4];                                                         \
    _Pragma("unroll")                                                           \
    for (int i = 0; i < 4; ++i) {                                               \
      af[i]  = *(const v8bf*)(&As[BI][ldsA + i * 512]);                         \
      bfr[i] = *(const v8bf*)(&Bs[BI][ldsB + i * 512]);                         \
    }                                                                           \
    _Pragma("unroll")                                                           \
    for (int i = 0; i < 4; ++i)                                                 \
      _Pragma("unroll")                                                         \
      for (int j = 0; j < 4; ++j)                                               \
        acc[i][j] = __builtin_amdgcn_mfma_f32_16x16x32_bf16(af[i], bfr[j],      \
                                                            acc[i][j], 0, 0, 0);\
  } while (0)

#define KITER(IT) do {                                                          \
    if constexpr ((IT) < 31) WAIT_VM4(); else WAIT_VM0();                       \
    __builtin_amdgcn_s_barrier();                                               \
    if constexpr ((IT) < 30) STAGE_T((IT) * 32 + 64, ((IT) + 2) % 3);           \
    COMPUTE((IT) % 3);                                                          \
  } while (0)

  if constexpr (MODE == 1) {
    // K = 1024 = 32 tiles, fully unrolled, constant-folded addresses
    STAGE_T(0, 0);
    STAGE_T(32, 1);
    KITER(0);  KITER(1);  KITER(2);  KITER(3);  KITER(4);  KITER(5);  KITER(6);
    KITER(7);  KITER(8);  KITER(9);  KITER(10); KITER(11); KITER(12); KITER(13);
    KITER(14); KITER(15); KITER(16); KITER(17); KITER(18); KITER(19); KITER(20);
    KITER(21); KITER(22); KITER(23); KITER(24); KITER(25); KITER(26); KITER(27);
    KITER(28); KITER(29); KITER(30); KITER(31);
  } else {
    // dynamic K (PV): rolling 3-buffer pipeline
    auto stage = [&](int k0, int buf) {
      __builtin_amdgcn_global_load_lds(GBL_AS(Arow0 + k0),
          LDS_AS(&As[buf][cb0 * 8]), 16, 0, 0);
      __builtin_amdgcn_global_load_lds(GBL_AS(Brow0 + k0),
          LDS_AS(&Bs[buf][cb0 * 8]), 16, 0, 0);
      __builtin_amdgcn_global_load_lds(GBL_AS(Arow1 + k0),
          LDS_AS(&As[buf][cb1 * 8]), 16, 0, 0);
      __builtin_amdgcn_global_load_lds(GBL_AS(Brow1 + k0),
          LDS_AS(&Bs[buf][cb1 * 8]), 16, 0, 0);
    };
    stage(0, 0);
    if (32 < kend) stage(32, 1);
    int bi = 0;
    for (int k0 = 0; k0 < kend; k0 += 32) {
      if (k0 + 32 < kend) WAIT_VM4(); else WAIT_VM0();
      __builtin_amdgcn_s_barrier();
      if (k0 + 64 < kend) stage(k0 + 64, bi == 0 ? 2 : bi - 1);
      v8bf af[4], bfr[4];
#pragma unroll
      for (int i = 0; i < 4; ++i) {
        af[i]  = *(const v8bf*)(&As[bi][ldsA + i * 512]);
        bfr[i] = *(const v8bf*)(&Bs[bi][ldsB + i * 512]);
      }
#pragma unroll
      for (int i = 0; i < 4; ++i)
#pragma unroll
        for (int j = 0; j < 4; ++j)
          acc[i][j] = __builtin_amdgcn_mfma_f32_16x16x32_bf16(af[i], bfr[j], acc[i][j], 0, 0, 0);
      bi = (bi == 2) ? 0 : bi + 1;
    }
  }
#undef KITER
#undef COMPUTE
#undef STAGE_T

  // epilogue: C/D layout col=lane&15, row=(lane>>4)*4+reg  [m89-verified]
  const int col0 = nb + wn + (l & 15);
  const int row0 = mb + wm + ((l >> 4) << 2);
  if constexpr (MODE == 1) {
    __hip_bfloat16* C = (__hip_bfloat16*)Cv + (long)z * sCb;
    float* srow = sums + z * 2048;
#pragma unroll
    for (int i = 0; i < 4; ++i)
#pragma unroll
      for (int r = 0; r < 4; ++r) {
        const int m = row0 + i * 16 + r;
        long ro = (long)m * ldc;
        float sp = 0.f;
#pragma unroll
        for (int j = 0; j < 4; ++j) {
          const int n = col0 + j * 16;
          float p = (n <= m) ? __expf(acc[i][j][r] * scale) : 0.0f;
          sp += p;
          C[ro + n] = __float2bfloat16(p);
        }
        sp += __shfl_xor(sp, 1);
        sp += __shfl_xor(sp, 2);
        sp += __shfl_xor(sp, 4);
        sp += __shfl_xor(sp, 8);
        if ((l & 15) == 0) atomicAdd(&srow[m], sp);
      }
  } else {
    float* C = (float*)Cv + (long)z * sCb;
    const float* srow = sums + z * 2048;
#pragma unroll
    for (int i = 0; i < 4; ++i)
#pragma unroll
      for (int r = 0; r < 4; ++r) {
        const int m = row0 + i * 16 + r;
        const float s = 1.0f / srow[m];
        long ro = (long)m * ldc;
#pragma unroll
        for (int j = 0; j < 4; ++j)
          C[ro + col0 + j * 16] = acc[i][j][r] * s;
      }
  }
}

__global__ __launch_bounds__(256, 3)
void gemm_score(const __hip_bfloat16* __restrict__ A, long sAb, int lda,
                const __hip_bfloat16* __restrict__ B, long sBb, int ldb,
                void* __restrict__ Cv, long sCb, int ldc,
                int K, float scale, float* __restrict__ sums) {
  gemm_nt_body<1>(A, sAb, lda, B, sBb, ldb, Cv, sCb, ldc, K, scale, sums);
}

__global__ __launch_bounds__(256, 3)
void gemm_pv(const __hip_bfloat16* __restrict__ A, long sAb, int lda,
             const __hip_bfloat16* __restrict__ B, long sBb, int ldb,
             void* __restrict__ Cv, long sCb, int ldc,
             int K, float scale, float* __restrict__ sums) {
  gemm_nt_body<2>(A, sAb, lda, B, sBb, ldb, Cv, sCb, ldc, K, scale, sums);
}

// ---------------- projection GEMM: 256x128 tile, 4 waves of 128x64 ----------------
// NEW this round. Same swizzle + triple-buffer + counted-vmcnt pipeline as the
// proven 128x128 kernel, but per-wave 8x4 fragments (128x64 output per wave):
// LDS traffic per MFMA drops 512B -> 384B, lifting the LDS-BW utilization cap
// from ~40% to ~55% (MODE0 measured MfmaUtil 28% with 0 bank conflicts, 11%
// VALUBusy, 21% HBM => LDS port is the binder).
// Per K-step: stage 24KB (A 16KB + B 8KB) = 6 global_load_lds/thread => vmcnt(6).
// LDS = 3 bufs * 24KB = 72KB -> 2 blocks/CU; grid 768 blocks = 3.0/CU exact.
// acc[8][4] = 128 regs -> ~210 unified VGPR, launch_bounds(256,2).
// z<2 -> bf16 out to qkv; z==2 -> transposed to vT (same epilogues, i<8).
__global__ __launch_bounds__(256, 2)
void gemm_proj(const __hip_bfloat16* __restrict__ A, int lda,
               const __hip_bfloat16* __restrict__ B, long sBb, int ldb,
               __hip_bfloat16* __restrict__ C, long sCb, int ldc,
               float scale, __hip_bfloat16* __restrict__ vTp) {
  const int tid = threadIdx.x;
  const int l = tid & 63, w = tid >> 6;
  const int z  = blockIdx.x >> 3;
  const int nb = (blockIdx.x & 7) << 7;   // N-tile: 128 wide
  const int mb = blockIdx.y << 8;         // M-tile: 256 tall

  B += (long)z * sBb;

  __shared__ alignas(16) __hip_bfloat16 As[3][256 * 32];   // 16KB per buf
  __shared__ alignas(16) __hip_bfloat16 Bs[3][128 * 32];   // 8KB per buf

  v4f acc[8][4] = {};
  const int wm = (w >> 1) << 7;   // 0 or 128
  const int wn = (w & 1) << 6;    // 0 or 64

  // staging sources: slot s covers LDS chunks s*256 + w*64 + l.
  // chunk q holds global (row=q>>2, col-chunk=(q&3)^((row>>1)&3)) [swizzle inv]
  const int qa0 = 0 * 256 + w * 64 + l, ra0 = qa0 >> 2;
  const int qa1 = 1 * 256 + w * 64 + l, ra1 = qa1 >> 2;
  const int qa2 = 2 * 256 + w * 64 + l, ra2 = qa2 >> 2;
  const int qa3 = 3 * 256 + w * 64 + l, ra3 = qa3 >> 2;
  const __hip_bfloat16* sA0 = A + (long)(mb + ra0) * lda + (((qa0 & 3) ^ ((ra0 >> 1) & 3)) << 3);
  const __hip_bfloat16* sA1 = A + (long)(mb + ra1) * lda + (((qa1 & 3) ^ ((ra1 >> 1) & 3)) << 3);
  const __hip_bfloat16* sA2 = A + (long)(mb + ra2) * lda + (((qa2 & 3) ^ ((ra2 >> 1) & 3)) << 3);
  const __hip_bfloat16* sA3 = A + (long)(mb + ra3) * lda + (((qa3 & 3) ^ ((ra3 >> 1) & 3)) << 3);
  const int qb0 = 0 * 256 + w * 64 + l, rb0 = qb0 >> 2;
  const int qb1 = 1 * 256 + w * 64 + l, rb1 = qb1 >> 2;
  const __hip_bfloat16* sB0 = B + (long)(nb + rb0) * ldb + (((qb0 & 3) ^ ((rb0 >> 1) & 3)) << 3);
  const __hip_bfloat16* sB1 = B + (long)(nb + rb1) * ldb + (((qb1 & 3) ^ ((rb1 >> 1) & 3)) << 3);

  // swizzled LDS read bases (swizzle invariant under +16 rows)
  const int arow = wm + (l & 15);
  const int ldsA = arow * 32 + ((((l >> 4) ^ ((arow >> 1) & 3))) << 3);
  const int brow = wn + (l & 15);
  const int ldsB = brow * 32 + ((((l >> 4) ^ ((brow >> 1) & 3))) << 3);

#define STAGE_P(K0, BUF) do {                                                   \
    __builtin_amdgcn_global_load_lds(GBL_AS(sA0 + (K0)),                        \
        LDS_AS(&As[BUF][0 * 2048 + w * 512]), 16, 0, 0);                        \
    __builtin_amdgcn_global_load_lds(GBL_AS(sA1 + (K0)),                        \
        LDS_AS(&As[BUF][1 * 2048 + w * 512]), 16, 0, 0);                        \
    __builtin_amdgcn_global_load_lds(GBL_AS(sA2 + (K0)),                        \
        LDS_AS(&As[BUF][2 * 2048 + w * 512]), 16, 0, 0);                        \
    __builtin_amdgcn_global_load_lds(GBL_AS(sA3 + (K0)),                        \
        LDS_AS(&As[BUF][3 * 2048 + w * 512]), 16, 0, 0);                        \
    __builtin_amdgcn_global_load_lds(GBL_AS(sB0 + (K0)),                        \
        LDS_AS(&Bs[BUF][0 * 2048 + w * 512]), 16, 0, 0);                        \
    __builtin_amdgcn_global_load_lds(GBL_AS(sB1 + (K0)),                        \
        LDS_AS(&Bs[BUF][1 * 2048 + w * 512]), 16, 0, 0);                        \
  } while (0)

#define COMPUTE_P(BI) do {                                                      \
    v8bf af[8], bfr[4];                                                         \
    _Pragma("unroll")                                                           \
    for (int i = 0; i < 8; ++i)                                                 \
      af[i]  = *(const v8bf*)(&As[BI][ldsA + i * 512]);                         \
    _Pragma("unroll")                                                           \
    for (int j = 0; j < 4; ++j)                                                 \
      bfr[j] = *(const v8bf*)(&Bs[BI][ldsB + j * 512]);                         \
    _Pragma("unroll")                                                           \
    for (int i = 0; i < 8; ++i)                                                 \
      _Pragma("unroll")                                                         \
      for (int j = 0; j < 4; ++j)                                               \
        acc[i][j] = __builtin_amdgcn_mfma_f32_16x16x32_bf16(af[i], bfr[j],      \
                                                            acc[i][j], 0, 0, 0);\
  } while (0)

#define KITER_P(IT) do {                                                        \
    if constexpr ((IT) < 31) WAIT_VM6(); else WAIT_VM0();                       \
    __builtin_amdgcn_s_barrier();                                               \
    if constexpr ((IT) < 30) STAGE_P((IT) * 32 + 64, ((IT) + 2) % 3);           \
    COMPUTE_P((IT) % 3);                                                        \
  } while (0)

  STAGE_P(0, 0);
  STAGE_P(32, 1);
  KITER_P(0);  KITER_P(1);  KITER_P(2);  KITER_P(3);  KITER_P(4);  KITER_P(5);
  KITER_P(6);  KITER_P(7);  KITER_P(8);  KITER_P(9);  KITER_P(10); KITER_P(11);
  KITER_P(12); KITER_P(13); KITER_P(14); KITER_P(15); KITER_P(16); KITER_P(17);
  KITER_P(18); KITER_P(19); KITER_P(20); KITER_P(21); KITER_P(22); KITER_P(23);
  KITER_P(24); KITER_P(25); KITER_P(26); KITER_P(27); KITER_P(28); KITER_P(29);
  KITER_P(30); KITER_P(31);
#undef KITER_P
#undef COMPUTE_P
#undef STAGE_P

  // epilogue: C/D layout col=lane&15, row=(lane>>4)*4+reg
  const int col0 = nb + wn + (l & 15);
  const int row0 = mb + wm + ((l >> 4) << 2);
  if (z < 2) {
    __hip_bfloat16* Cz = C + (long)z * sCb;
#pragma unroll
    for (int i = 0; i < 8; ++i)
#pragma unroll
      for (int r = 0; r < 4; ++r) {
        long ro = (long)(row0 + i * 16 + r) * ldc;
#pragma unroll
        for (int j = 0; j < 4; ++j)
          Cz[ro + col0 + j * 16] = __float2bfloat16(acc[i][j][r] * scale);
      }
  } else {
    // V projection: write transposed into vT[b][col][seq], 8B packed stores
    const long b = row0 >> 11;
    const int seq0 = row0 & 2047;
#pragma unroll
    for (int i = 0; i < 8; ++i)
#pragma unroll
      for (int j = 0; j < 4; ++j) {
        union { __hip_bfloat16 h[4]; uint2 u; } pk;
#pragma unroll
        for (int r = 0; r < 4; ++r) pk.h[r] = __float2bfloat16(acc[i][j][r]);
        *(uint2*)(vTp + b * 2097152 + (long)(col0 + j * 16) * 2048 +
                  (seq0 + i * 16)) = pk.u;
      }
  }
}

// ---------------- launch ----------------
extern "C" void kernel_launch(void* const* d_in, const int* in_sizes, int n_in,
                              void* d_out, int out_size, void* d_ws, size_t ws_size,
                              hipStream_t stream) {
  const float* x  = (const float*)d_in[0];
  const float* Wq = (const float*)d_in[1];
  const float* Wk = (const float*)d_in[2];
  const float* Wv = (const float*)d_in[3];
  float* out = (float*)d_out;
  char* ws = (char*)d_ws;

  // ws layout (bytes):
  //   qkv bf16 [3][8192][1024]   @ 0          (48 MB; v-slice unused now)
  //   vT  bf16 [4][1024][2048]   @ 50331648   (16 MB)
  //   xb  bf16 [8192][1024]      @ 67108864   (16 MB, dead after proj)
  //   Wb  bf16 [3][1024][1024]   @ 83886080   ( 6 MB, dead after proj)
  //   P   bf16 [4][2048][2048]   @ 67108864   (32 MB, overlaps dead xb/Wb)
  //   sums fp32 [8192]           @ 100663296  (32 KB)
  __hip_bfloat16* qkv = (__hip_bfloat16*)ws;
  __hip_bfloat16* vT  = (__hip_bfloat16*)(ws + 50331648);
  __hip_bfloat16* xb  = (__hip_bfloat16*)(ws + 67108864);
  __hip_bfloat16* Wb  = (__hip_bfloat16*)(ws + 83886080);
  __hip_bfloat16* P   = (__hip_bfloat16*)(ws + 67108864);
  float* sums         = (float*)(ws + 100663296);

  hipMemsetAsync(sums, 0, 8192 * sizeof(float), stream);

  cast_f32_bf16<<<8192, 256, 0, stream>>>(x, xb, 8388608);
  cast_w3<<<3072, 256, 0, stream>>>(Wq, Wk, Wv, Wb);

  // qkv projections; z==2 (V) written transposed into vT by the epilogue
  gemm_proj<<<dim3(24, 32, 1), 256, 0, stream>>>(
      xb, 1024, Wb, 1048576L, 1024, qkv, 8388608L, 1024, 1.0f, vT);

  // P = exp((q@k^T)/32) causal, bf16, fused row-sums (triangular grid: 136*4)
  gemm_score<<<dim3(544, 1, 1), 256, 0, stream>>>(
      qkv, 2097152L, 1024, qkv + 8388608, 2097152L, 1024,
      P, 4194304L, 2048, 1024, 0.03125f, sums);

  // out = (P @ vT^T) / rowsum, causal K-limit, pair-balanced flat grid
  gemm_pv<<<dim3(512, 1, 1), 256, 0, stream>>>(
      P, 4194304L, 2048, vT, 2097152L, 2048,
      out, 2097152L, 1024, 2048, 1.0f, sums);
}